// Round 1
// baseline (28.895 us; speedup 1.0000x reference)
//
#include <hip/hip_runtime.h>
#include <hip/hip_bf16.h>

// 3D inverse Haar wavelet recombination.
// Input  x : (B=2, 8*C=256, D=32, H=32, W=32) fp32, band index = 4i+2j+k in
//            the high bits of the channel dim (c8 = band*32 + c).
// Output   : (B=2, C=32, 2D=64, 2H=64, 2W=64) fp32,
//            out[b,c,2d+p,2h+q,2w+r] = sum_{ijk} (-1)^(ip+jq+kr) x[b,(4i+2j+k)*C+c,d,h,w]
//
// Each thread handles 2 consecutive w coarse voxels:
//   loads  : 8 bands x float2   (coalesced, 8 streams)
//   stores : 4 x float4         (coalesced, 4 fine rows)
// Butterfly is separable: 3 stages x 8 adds, applied to both voxels (e=0,1).

#define C_DIM   32
#define D_DIM   32
#define H_DIM   32
#define W_DIM   32
#define W2      (W_DIM / 2)                 // 16 w-pairs
#define SPATIAL (D_DIM * H_DIM * W_DIM)     // 32768
#define BAND_STRIDE (C_DIM * SPATIAL)       // 1048576 floats between bands
#define OUT_CH_STRIDE (8 * SPATIAL)         // 64*64*64 = 262144

__global__ __launch_bounds__(256) void iwt3d_kernel(const float* __restrict__ x,
                                                    float* __restrict__ out) {
    int t = blockIdx.x * blockDim.x + threadIdx.x;
    // total threads = B * C * D * H * W2 = 2*32*32*32*16 = 1,048,576

    int w2 = t & (W2 - 1);        int r = t >> 4;
    int h  = r & (H_DIM - 1);     r >>= 5;
    int d  = r & (D_DIM - 1);     r >>= 5;
    int c  = r & (C_DIM - 1);     r >>= 5;
    int b  = r;                   // 0..1

    size_t in_base = (size_t)b * (8 * BAND_STRIDE)
                   + (size_t)c * SPATIAL
                   + (size_t)d * (H_DIM * W_DIM)
                   + (size_t)h * W_DIM
                   + (size_t)(w2 * 2);

    // v[band][e] : band = 4i+2j+k, e = which of the 2 voxels
    float v[8][2];
#pragma unroll
    for (int s = 0; s < 8; ++s) {
        float2 ld = *reinterpret_cast<const float2*>(x + in_base + (size_t)s * BAND_STRIDE);
        v[s][0] = ld.x;
        v[s][1] = ld.y;
    }

    // Stage 1 (over k -> r): tk[4i+2j+r]
    float tk[8][2];
#pragma unroll
    for (int ij = 0; ij < 4; ++ij) {
#pragma unroll
        for (int e = 0; e < 2; ++e) {
            tk[ij * 2 + 0][e] = v[ij * 2 + 0][e] + v[ij * 2 + 1][e];
            tk[ij * 2 + 1][e] = v[ij * 2 + 0][e] - v[ij * 2 + 1][e];
        }
    }

    // Stage 2 (over j -> q): uq[4i+2q+r]
    float uq[8][2];
#pragma unroll
    for (int i = 0; i < 2; ++i) {
#pragma unroll
        for (int rr = 0; rr < 2; ++rr) {
#pragma unroll
            for (int e = 0; e < 2; ++e) {
                uq[i * 4 + 0 + rr][e] = tk[i * 4 + rr][e] + tk[i * 4 + 2 + rr][e];
                uq[i * 4 + 2 + rr][e] = tk[i * 4 + rr][e] - tk[i * 4 + 2 + rr][e];
            }
        }
    }

    // Stage 3 (over i -> p): o[4p+2q+r]
    float o[8][2];
#pragma unroll
    for (int qr = 0; qr < 4; ++qr) {
#pragma unroll
        for (int e = 0; e < 2; ++e) {
            o[0 + qr][e] = uq[qr][e] + uq[4 + qr][e];
            o[4 + qr][e] = uq[qr][e] - uq[4 + qr][e];
        }
    }

    // Output: out[b, c, 2d+p, 2h+q, 4*w2 + 2e + r]
    size_t out_cbase = ((size_t)(b * C_DIM + c)) * OUT_CH_STRIDE;
#pragma unroll
    for (int p = 0; p < 2; ++p) {
#pragma unroll
        for (int q = 0; q < 2; ++q) {
            size_t off = out_cbase
                       + (size_t)(2 * d + p) * (2 * H_DIM * 2 * W_DIM)
                       + (size_t)(2 * h + q) * (2 * W_DIM)
                       + (size_t)(4 * w2);
            float4 st;
            st.x = o[p * 4 + q * 2 + 0][0];  // e=0, r=0
            st.y = o[p * 4 + q * 2 + 1][0];  // e=0, r=1
            st.z = o[p * 4 + q * 2 + 0][1];  // e=1, r=0
            st.w = o[p * 4 + q * 2 + 1][1];  // e=1, r=1
            *reinterpret_cast<float4*>(out + off) = st;
        }
    }
}

extern "C" void kernel_launch(void* const* d_in, const int* in_sizes, int n_in,
                              void* d_out, int out_size, void* d_ws, size_t ws_size,
                              hipStream_t stream) {
    const float* x = (const float*)d_in[0];
    float* out = (float*)d_out;

    // B*C*D*H*W2 = 2*32*32*32*16 = 1,048,576 threads
    const int total = 2 * C_DIM * D_DIM * H_DIM * W2;
    const int block = 256;
    const int grid = total / block;  // 4096
    iwt3d_kernel<<<grid, block, 0, stream>>>(x, out);
}